// Round 7
// baseline (167.029 us; speedup 1.0000x reference)
//
#include <hip/hip_runtime.h>
#include <hip/hip_fp16.h>

typedef __attribute__((ext_vector_type(8))) short short8;   // 8 bf16
typedef __attribute__((ext_vector_type(4))) float f32x4;    // MFMA acc

constexpr int kB = 8;
constexpr int kN = 256;
constexpr int kD = 1024;
constexpr int kP = 512;
constexpr int kM = kB * kN;  // 2048

// v_pk_max_f16 — ROCm headers lack __hmax2; emit the VOP3P op directly.
__device__ __forceinline__ __half2 pk_max2(__half2 a, __half2 b) {
    unsigned ua = *reinterpret_cast<unsigned*>(&a);
    unsigned ub = *reinterpret_cast<unsigned*>(&b);
    unsigned ur;
    asm("v_pk_max_f16 %0, %1, %2" : "=v"(ur) : "v"(ua), "v"(ub));
    return *reinterpret_cast<__half2*>(&ur);
}

// ---------------------------------------------------------------------------
// cvt_kernel: fp32 -> bf16 for x and the 4 projection weights (merged into
// one [2048][1024] matrix wb). Tail blocks (>=2048) initialize the WHOLE
// output buffer: bigram cells = bo (bigram_kernel atomicAdds partials onto
// them), start = bs2, end = be2 (proj_mfma atomicAdds head dots onto them).
// ---------------------------------------------------------------------------
__global__ __launch_bounds__(256) void cvt_kernel(
    const float* __restrict__ x,
    const float* __restrict__ Wl, const float* __restrict__ Wr,
    const float* __restrict__ Ws1, const float* __restrict__ We1,
    const float* __restrict__ bo, const float* __restrict__ bs2,
    const float* __restrict__ be2,
    unsigned short* __restrict__ xb, unsigned short* __restrict__ wb,
    float* __restrict__ outall)
{
    const int bid = blockIdx.x;
    if (bid >= 2048) {  // init 528384 output elements as 132096 float4s
        const int idx = (bid - 2048) * 256 + threadIdx.x;
        const int e = idx * 4;
        float bval;
        if (e < 524288)      bval = bo[0];
        else if (e < 526336) bval = bs2[0];
        else                 bval = be2[0];
        float4 v = {bval, bval, bval, bval};
        *reinterpret_cast<float4*>(&outall[e]) = v;
        return;
    }
    const int g = bid * 256 + threadIdx.x;  // 0..524287 groups of 8
    const float* src;
    unsigned short* dst;
    if (g < 262144) {
        src = x + (size_t)g * 8;
        dst = xb + (size_t)g * 8;
    } else {
        const int gg = g - 262144;
        const int w = gg >> 16;        // 0=Wl 1=Wr 2=Ws1 3=We1
        const int r = gg & 65535;
        const float* s = (w == 0) ? Wl : (w == 1) ? Wr : (w == 2) ? Ws1 : We1;
        src = s + (size_t)r * 8;
        dst = wb + ((size_t)w << 19) + (size_t)r * 8;
    }
    const float4 a = *reinterpret_cast<const float4*>(src);
    const float4 b = *reinterpret_cast<const float4*>(src + 4);
    const float v[8] = {a.x, a.y, a.z, a.w, b.x, b.y, b.z, b.w};
    short8 o;
#pragma unroll
    for (int i = 0; i < 8; ++i) {
        unsigned u = __float_as_uint(v[i]);
        u = u + 0x7FFF + ((u >> 16) & 1);  // RTNE
        o[i] = (short)(u >> 16);
    }
    *reinterpret_cast<short8*>(dst) = o;
}

// ---------------------------------------------------------------------------
// proj_mfma (R5 config — best measured): merged GEMM C[r][q], q in [0,2048).
// BM=BN=64, BK=64 -> grid 32x32 = 1024 blocks (4/CU). 4 waves (2x2), each
// wave a 32x32 output (2x2 fragments of 16x16x32, 2 k-subs per BK).
// LDS rows 128 B, XOR-swizzle byte^=(row&7)<<4 applied BOTH sides (rule #21).
// z = q0>>9: 0->left (bias bl, f16 transposed [b][p][j]); 1->right;
//            2,3->heads fused (relu, dot Ws2/We2, shfl-reduce, atomicAdd).
// ---------------------------------------------------------------------------
__global__ __launch_bounds__(256) void proj_mfma(
    const unsigned short* __restrict__ xb, const unsigned short* __restrict__ wb,
    const float* __restrict__ bl, const float* __restrict__ bs1,
    const float* __restrict__ be1,
    const float* __restrict__ Ws2, const float* __restrict__ We2,
    __half* __restrict__ left_h, __half* __restrict__ right_h,
    float* __restrict__ out_start, float* __restrict__ out_end)
{
    __shared__ unsigned short As[2][64 * 64];  // 8 KB x2
    __shared__ unsigned short Bs[2][64 * 64];  // 8 KB x2

    const int r0 = blockIdx.x * 64;
    const int q0 = blockIdx.y * 64;
    const int z  = q0 >> 9;
    const int t = threadIdx.x, wid = t >> 6, lane = t & 63;
    const int wr = wid >> 1, wc = wid & 1;

    f32x4 acc[2][2] = {};

    const int srow0 = wid * 16 + (lane >> 3);          // call 0 row
    const int scolh = ((lane & 7) ^ (lane >> 3)) << 3; // swizzled col (halves)
    const unsigned short* gA0 = xb + (size_t)(r0 + srow0) * kD + scolh;
    const unsigned short* gA1 = gA0 + (size_t)8 * kD;
    const unsigned short* gB0 = wb + (size_t)(q0 + srow0) * kD + scolh;
    const unsigned short* gB1 = gB0 + (size_t)8 * kD;

#define STAGE(buf, k0) do { \
    __builtin_amdgcn_global_load_lds( \
        (const __attribute__((address_space(1))) void*)(gA0 + (k0)), \
        (__attribute__((address_space(3))) void*)((char*)&As[buf][0] + wid * 2048), 16, 0, 0); \
    __builtin_amdgcn_global_load_lds( \
        (const __attribute__((address_space(1))) void*)(gA1 + (k0)), \
        (__attribute__((address_space(3))) void*)((char*)&As[buf][0] + wid * 2048 + 1024), 16, 0, 0); \
    __builtin_amdgcn_global_load_lds( \
        (const __attribute__((address_space(1))) void*)(gB0 + (k0)), \
        (__attribute__((address_space(3))) void*)((char*)&Bs[buf][0] + wid * 2048), 16, 0, 0); \
    __builtin_amdgcn_global_load_lds( \
        (const __attribute__((address_space(1))) void*)(gB1 + (k0)), \
        (__attribute__((address_space(3))) void*)((char*)&Bs[buf][0] + wid * 2048 + 1024), 16, 0, 0); \
} while (0)

    const int sw = (lane & 7) << 4;
    const int cb0 = (lane >> 4) * 16;
    const int rA = wr * 32 + (lane & 15);
    const int rB = wc * 32 + (lane & 15);

    STAGE(0, 0);
    __syncthreads();
    int cur = 0;
    for (int k0 = 0; k0 < kD; k0 += 64) {
        if (k0 + 64 < kD) STAGE(cur ^ 1, k0 + 64);
        short8 a[2][2], b[2][2];
#pragma unroll
        for (int m = 0; m < 2; ++m)
#pragma unroll
            for (int ks = 0; ks < 2; ++ks) {
                a[m][ks] = *reinterpret_cast<const short8*>(
                    (const char*)&As[cur][0] +
                    (rA + m * 16) * 128 + ((ks * 64 + cb0) ^ sw));
                b[m][ks] = *reinterpret_cast<const short8*>(
                    (const char*)&Bs[cur][0] +
                    (rB + m * 16) * 128 + ((ks * 64 + cb0) ^ sw));
            }
#pragma unroll
        for (int m = 0; m < 2; ++m)
#pragma unroll
            for (int n = 0; n < 2; ++n)
#pragma unroll
                for (int ks = 0; ks < 2; ++ks)
                    acc[m][n] = __builtin_amdgcn_mfma_f32_16x16x32_bf16(
                        a[m][ks], b[n][ks], acc[m][n], 0, 0, 0);
        __syncthreads();
        cur ^= 1;
    }
#undef STAGE

    // C/D layout: col = lane&15, row = (lane>>4)*4 + reg  [m89]
    int pcol[2]; float bq[2];
#pragma unroll
    for (int n = 0; n < 2; ++n) {
        pcol[n] = (q0 & 511) + wc * 32 + n * 16 + (lane & 15);
        bq[n] = (z == 0) ? bl[pcol[n]] : (z == 2) ? bs1[pcol[n]]
              : (z == 3) ? be1[pcol[n]] : 0.f;
    }
    if (z < 2) {
        __half* dst = (z == 0) ? left_h : right_h;
        const int bb = r0 >> 8;
        const int jbase = (r0 & 255) + wr * 32 + (lane >> 4) * 4;
#pragma unroll
        for (int n = 0; n < 2; ++n) {
            __half* drow = dst + (size_t)(bb * kP + pcol[n]) * kN;
#pragma unroll
            for (int m = 0; m < 2; ++m) {
                const f32x4 c = acc[m][n];
                __half2 h01 = __floats2half2_rn(c[0] + bq[n], c[1] + bq[n]);
                __half2 h23 = __floats2half2_rn(c[2] + bq[n], c[3] + bq[n]);
                uint2 u;
                u.x = *reinterpret_cast<unsigned*>(&h01);
                u.y = *reinterpret_cast<unsigned*>(&h23);
                *reinterpret_cast<uint2*>(&drow[jbase + m * 16]) = u;
            }
        }
    } else {
        const float* Wv = (z == 2) ? Ws2 : We2;
        float* outh = (z == 2) ? out_start : out_end;
        const float w0 = Wv[pcol[0]], w1 = Wv[pcol[1]];
        const int rbase = r0 + wr * 32 + (lane >> 4) * 4;
#pragma unroll
        for (int m = 0; m < 2; ++m) {
#pragma unroll
            for (int q = 0; q < 4; ++q) {
                float s = fmaxf(acc[m][0][q] + bq[0], 0.f) * w0 +
                          fmaxf(acc[m][1][q] + bq[1], 0.f) * w1;
                s += __shfl_xor(s, 1); s += __shfl_xor(s, 2);
                s += __shfl_xor(s, 4); s += __shfl_xor(s, 8);
                if ((lane & 15) == 0)
                    atomicAdd(&outh[rbase + m * 16 + q], s);
            }
        }
    }
}

// ---------------------------------------------------------------------------
// bigram_kernel: out[b][i][j] += sum_{p in chunk pc} relu(l[j][p]+r[i][p])*Wo[p]
// bz = b*8 + pc (P split into 8 chunks of 64 -> 1024 blocks, 4/CU).
// R4 geometry (single 64-p stage, f16 pk math, rs pre-duplicated {r,r}),
// epilogue = 16 atomicAdds/thread directly into d_out (pre-init'd = bo by
// cvt_kernel; same graph, ordered). No part buffer, no reduce kernel.
// ---------------------------------------------------------------------------
__global__ __launch_bounds__(256) void bigram_kernel(
    const __half* __restrict__ left_h, const __half* __restrict__ right_h,
    const float* __restrict__ Wo, float* __restrict__ out)
{
    __shared__ __half ls[64][64];     // [p][j]  8 KB
    __shared__ __half2 rs2[64][64];   // [p][i] dup'd  16 KB
    __shared__ __half2 wos[64];

    const int bz = blockIdx.z, b = bz >> 3, pc = bz & 7;
    const int i0 = blockIdx.y * 64, j0 = blockIdx.x * 64;
    const int t = threadIdx.x, wid = t >> 6, lane = t & 63;
    const int tj = t & 15, ti = t >> 4;

    const __half* lbase = left_h  + (size_t)(b * kP + pc * 64) * kN;
    const __half* rbase = right_h + (size_t)(b * kP + pc * 64) * kN;

    // ls: direct global->LDS (linear dest, 1 KB per wave-call)
#pragma unroll
    for (int h = 0; h < 2; ++h) {
        const int row = wid * 16 + h * 8 + (lane >> 3);
        __builtin_amdgcn_global_load_lds(
            (const __attribute__((address_space(1))) void*)
                (lbase + (size_t)row * kN + j0 + (lane & 7) * 8),
            (__attribute__((address_space(3))) void*)
                ((char*)&ls[0][0] + wid * 2048 + h * 1024),
            16, 0, 0);
    }
    // rs2: reg-staged with in-register duplication {r,r}
    uint2 rload[4];
#pragma unroll
    for (int h = 0; h < 4; ++h) {
        const int idx = h * 256 + t, pp = idx >> 4, iq = idx & 15;
        rload[h] = *reinterpret_cast<const uint2*>(&rbase[(size_t)pp * kN + i0 + iq * 4]);
    }
    if (t < 64) wos[t] = __float2half2_rn(Wo[pc * 64 + t]);
#pragma unroll
    for (int h = 0; h < 4; ++h) {
        const int idx = h * 256 + t, pp = idx >> 4, iq = idx & 15;
        const unsigned lo = rload[h].x, hi = rload[h].y;
        uint4 d;
        d.x = (lo & 0xFFFFu) | (lo << 16);
        d.y = (lo >> 16)     | (lo & 0xFFFF0000u);
        d.z = (hi & 0xFFFFu) | (hi << 16);
        d.w = (hi >> 16)     | (hi & 0xFFFF0000u);
        *reinterpret_cast<uint4*>(&rs2[pp][iq * 4]) = d;
    }
    __syncthreads();

    const __half2 zero2 = __float2half2_rn(0.f);
    __half2 acc2[4][2];
#pragma unroll
    for (int ii = 0; ii < 4; ++ii)
#pragma unroll
        for (int jp = 0; jp < 2; ++jp) acc2[ii][jp] = zero2;

#pragma unroll 8
    for (int kk = 0; kk < 64; ++kk) {
        const __half2 wo2 = wos[kk];
        union { uint2 u; __half2 h[2]; } L;
        L.u = *reinterpret_cast<const uint2*>(&ls[kk][tj * 4]);
        union { uint4 u; __half2 h[4]; } R;
        R.u = *reinterpret_cast<const uint4*>(&rs2[kk][ti * 4]);
#pragma unroll
        for (int ii = 0; ii < 4; ++ii)
#pragma unroll
            for (int jp = 0; jp < 2; ++jp) {
                __half2 s = __hadd2(R.h[ii], L.h[jp]);
                s = pk_max2(s, zero2);
                acc2[ii][jp] = __hfma2(s, wo2, acc2[ii][jp]);
            }
    }

#pragma unroll
    for (int ii = 0; ii < 4; ++ii) {
        const float2 a = __half22float2(acc2[ii][0]);
        const float2 c = __half22float2(acc2[ii][1]);
        float* row = out + ((size_t)b * kN + (i0 + ti * 4 + ii)) * kN + j0 + tj * 4;
        atomicAdd(row + 0, a.x);
        atomicAdd(row + 1, a.y);
        atomicAdd(row + 2, c.x);
        atomicAdd(row + 3, c.y);
    }
}

// ---------------------------------------------------------------------------
extern "C" void kernel_launch(void* const* d_in, const int* in_sizes, int n_in,
                              void* d_out, int out_size, void* d_ws, size_t ws_size,
                              hipStream_t stream) {
    const float* x   = (const float*)d_in[0];
    const float* Wl  = (const float*)d_in[1];
    const float* bl  = (const float*)d_in[2];
    const float* Wr  = (const float*)d_in[3];
    const float* Wo  = (const float*)d_in[4];
    const float* bo  = (const float*)d_in[5];
    const float* Ws1 = (const float*)d_in[6];
    const float* bs1 = (const float*)d_in[7];
    const float* Ws2 = (const float*)d_in[8];
    const float* bs2 = (const float*)d_in[9];
    const float* We1 = (const float*)d_in[10];
    const float* be1 = (const float*)d_in[11];
    const float* We2 = (const float*)d_in[12];
    const float* be2 = (const float*)d_in[13];

    float* out        = (float*)d_out;
    float* out_bigram = out;                          // [B,N,N,1]
    float* out_start  = out + (size_t)kB * kN * kN;   // [B,N,1]
    float* out_end    = out_start + (size_t)kB * kN;  // [B,N,1]

    // ws layout (12 MB used):
    //   0-2 MB   left_h  (f16, [b][p][j])
    //   2-4 MB   right_h (f16, [b][p][i])
    //   4-8 MB   xb (bf16)
    //   8-12 MB  wb (bf16)
    __half* left_h  = (__half*)d_ws;
    __half* right_h = left_h + (size_t)1048576;
    unsigned short* xb = (unsigned short*)((char*)d_ws + (size_t)4 * 1024 * 1024);
    unsigned short* wb = xb + (size_t)2097152;

    cvt_kernel<<<2564, 256, 0, stream>>>(
        x, Wl, Wr, Ws1, We1, bo, bs2, be2, xb, wb, out);

    proj_mfma<<<dim3(32, 32), 256, 0, stream>>>(
        xb, wb, bl, bs1, be1, Ws2, We2, left_h, right_h, out_start, out_end);

    bigram_kernel<<<dim3(4, 4, 64), 256, 0, stream>>>(
        left_h, right_h, Wo, out_bigram);
}

// Round 8
// 153.284 us; speedup vs baseline: 1.0897x; 1.0897x over previous
//
#include <hip/hip_runtime.h>
#include <hip/hip_fp16.h>

typedef __attribute__((ext_vector_type(8))) short short8;   // 8 bf16
typedef __attribute__((ext_vector_type(4))) float f32x4;    // MFMA acc

constexpr int kB = 8;
constexpr int kN = 256;
constexpr int kD = 1024;
constexpr int kP = 512;
constexpr int kM = kB * kN;  // 2048

// v_pk_max_f16 — ROCm headers lack __hmax2; emit the VOP3P op directly.
__device__ __forceinline__ __half2 pk_max2(__half2 a, __half2 b) {
    unsigned ua = *reinterpret_cast<unsigned*>(&a);
    unsigned ub = *reinterpret_cast<unsigned*>(&b);
    unsigned ur;
    asm("v_pk_max_f16 %0, %1, %2" : "=v"(ur) : "v"(ua), "v"(ub));
    return *reinterpret_cast<__half2*>(&ur);
}

// ---------------------------------------------------------------------------
// cvt_kernel: fp32 -> bf16 for x and the 4 projection weights (merged into
// one [2048][1024] matrix wb). Tail blocks (>=2048) init out_start/out_end
// with the head biases (proj_mfma atomicAdds partial head dots onto them).
// ---------------------------------------------------------------------------
__global__ __launch_bounds__(256) void cvt_kernel(
    const float* __restrict__ x,
    const float* __restrict__ Wl, const float* __restrict__ Wr,
    const float* __restrict__ Ws1, const float* __restrict__ We1,
    const float* __restrict__ bs2, const float* __restrict__ be2,
    unsigned short* __restrict__ xb, unsigned short* __restrict__ wb,
    float* __restrict__ out_start, float* __restrict__ out_end)
{
    const int bid = blockIdx.x;
    if (bid >= 2048) {  // head-bias init: 4096 elements
        const int idx = (bid - 2048) * 256 + threadIdx.x;
        if (idx < 2048) out_start[idx] = bs2[0];
        else            out_end[idx - 2048] = be2[0];
        return;
    }
    const int g = bid * 256 + threadIdx.x;  // 0..524287 groups of 8
    const float* src;
    unsigned short* dst;
    if (g < 262144) {
        src = x + (size_t)g * 8;
        dst = xb + (size_t)g * 8;
    } else {
        const int gg = g - 262144;
        const int w = gg >> 16;        // 0=Wl 1=Wr 2=Ws1 3=We1
        const int r = gg & 65535;
        const float* s = (w == 0) ? Wl : (w == 1) ? Wr : (w == 2) ? Ws1 : We1;
        src = s + (size_t)r * 8;
        dst = wb + ((size_t)w << 19) + (size_t)r * 8;
    }
    const float4 a = *reinterpret_cast<const float4*>(src);
    const float4 b = *reinterpret_cast<const float4*>(src + 4);
    const float v[8] = {a.x, a.y, a.z, a.w, b.x, b.y, b.z, b.w};
    short8 o;
#pragma unroll
    for (int i = 0; i < 8; ++i) {
        unsigned u = __float_as_uint(v[i]);
        u = u + 0x7FFF + ((u >> 16) & 1);  // RTNE
        o[i] = (short)(u >> 16);
    }
    *reinterpret_cast<short8*>(dst) = o;
}

// ---------------------------------------------------------------------------
// proj_mfma: merged GEMM  C[r][q] = sum_d xb[r][d] * wb[q][d],  q in [0,2048)
// BM=BN=256, BK=32 -> grid 8x8 = 64 blocks (feed traffic 64 MB vs 256 MB at
// 64^2 tiles -- the R7-diagnosed L3-feed bound). 512 threads = 8 waves
// (2 wr x 4 wc); each wave a 128x64 output = 8(m) x 4(n) fragments.
// Block decode: by = L&7 (same-B blocks share an XCD -> B L2-resident),
// bx = L>>3. LDS rows 64 B; swizzle slot ^= row&3 applied BOTH sides
// (linear global_load_lds dest + inverse-swizzled source, rule #21).
// z = q0>>9: 0->left (bias bl, f16 transposed [b][p][j]); 1->right;
//            2,3->heads fused (relu, dot Ws2/We2, shfl-reduce, atomicAdd).
// ---------------------------------------------------------------------------
__global__ __launch_bounds__(512) void proj_mfma(
    const unsigned short* __restrict__ xb, const unsigned short* __restrict__ wb,
    const float* __restrict__ bl, const float* __restrict__ bs1,
    const float* __restrict__ be1,
    const float* __restrict__ Ws2, const float* __restrict__ We2,
    __half* __restrict__ left_h, __half* __restrict__ right_h,
    float* __restrict__ out_start, float* __restrict__ out_end)
{
    __shared__ unsigned short As[2][256 * 32];  // 16 KB x2
    __shared__ unsigned short Bs[2][256 * 32];  // 16 KB x2

    const int L = blockIdx.x;
    const int by = L & 7, bx = L >> 3;
    const int r0 = bx * 256;
    const int q0 = by * 256;
    const int z  = q0 >> 9;
    const int t = threadIdx.x, wid = t >> 6, lane = t & 63;
    const int wr = wid >> 2, wc = wid & 3;  // 2 x 4 waves

    f32x4 acc[8][4] = {};

    // staging: per wave 2 calls for A, 2 for B; call c covers 16 rows.
    // LDS linear: row = wid*32 + c*16 + (lane>>2), slot_dest = lane&3 (16B).
    // source slot = slot_dest ^ (row&3), row&3 = (lane>>2)&3.
    const int srow0 = wid * 32 + (lane >> 2);
    const int scolh = (((lane & 3) ^ ((lane >> 2) & 3))) << 3;  // halves
    const unsigned short* gA0 = xb + (size_t)(r0 + srow0) * kD + scolh;
    const unsigned short* gA1 = gA0 + (size_t)16 * kD;
    const unsigned short* gB0 = wb + (size_t)(q0 + srow0) * kD + scolh;
    const unsigned short* gB1 = gB0 + (size_t)16 * kD;

#define STAGE(buf, k0) do { \
    __builtin_amdgcn_global_load_lds( \
        (const __attribute__((address_space(1))) void*)(gA0 + (k0)), \
        (__attribute__((address_space(3))) void*)((char*)&As[buf][0] + wid * 2048), 16, 0, 0); \
    __builtin_amdgcn_global_load_lds( \
        (const __attribute__((address_space(1))) void*)(gA1 + (k0)), \
        (__attribute__((address_space(3))) void*)((char*)&As[buf][0] + wid * 2048 + 1024), 16, 0, 0); \
    __builtin_amdgcn_global_load_lds( \
        (const __attribute__((address_space(1))) void*)(gB0 + (k0)), \
        (__attribute__((address_space(3))) void*)((char*)&Bs[buf][0] + wid * 2048), 16, 0, 0); \
    __builtin_amdgcn_global_load_lds( \
        (const __attribute__((address_space(1))) void*)(gB1 + (k0)), \
        (__attribute__((address_space(3))) void*)((char*)&Bs[buf][0] + wid * 2048 + 1024), 16, 0, 0); \
} while (0)

    // fragment reads: row = base + (lane&15) (bases multiple of 16 ->
    // row&3 == lane&3); logical slot = lane>>4; swizzled ^= lane&3.
    const int fslot = ((lane >> 4) ^ (lane & 3)) << 4;  // byte offset in row
    const int rA = wr * 128 + (lane & 15);
    const int rB = wc * 64 + (lane & 15);

    STAGE(0, 0);
    __syncthreads();
    int cur = 0;
    for (int k0 = 0; k0 < kD; k0 += 32) {
        if (k0 + 32 < kD) STAGE(cur ^ 1, k0 + 32);
        short8 a[8], b[4];
#pragma unroll
        for (int m = 0; m < 8; ++m)
            a[m] = *reinterpret_cast<const short8*>(
                (const char*)&As[cur][0] + (rA + m * 16) * 64 + fslot);
#pragma unroll
        for (int n = 0; n < 4; ++n)
            b[n] = *reinterpret_cast<const short8*>(
                (const char*)&Bs[cur][0] + (rB + n * 16) * 64 + fslot);
#pragma unroll
        for (int m = 0; m < 8; ++m)
#pragma unroll
            for (int n = 0; n < 4; ++n)
                acc[m][n] = __builtin_amdgcn_mfma_f32_16x16x32_bf16(
                    a[m], b[n], acc[m][n], 0, 0, 0);
        __syncthreads();
        cur ^= 1;
    }
#undef STAGE

    // C/D layout: col = lane&15, row = (lane>>4)*4 + reg  [m89]
    int pcol[4]; float bq[4];
#pragma unroll
    for (int n = 0; n < 4; ++n) {
        pcol[n] = (q0 & 511) + wc * 64 + n * 16 + (lane & 15);
        bq[n] = (z == 0) ? bl[pcol[n]] : (z == 2) ? bs1[pcol[n]]
              : (z == 3) ? be1[pcol[n]] : 0.f;
    }
    if (z < 2) {
        __half* dst = (z == 0) ? left_h : right_h;
        const int bb = r0 >> 8;  // r0 multiple of 256 -> bb = batch
        const int jbase = wr * 128 + (lane >> 4) * 4;
#pragma unroll
        for (int n = 0; n < 4; ++n) {
            __half* drow = dst + (size_t)(bb * kP + pcol[n]) * kN;
#pragma unroll
            for (int m = 0; m < 8; ++m) {
                const f32x4 c = acc[m][n];
                __half2 h01 = __floats2half2_rn(c[0] + bq[n], c[1] + bq[n]);
                __half2 h23 = __floats2half2_rn(c[2] + bq[n], c[3] + bq[n]);
                uint2 u;
                u.x = *reinterpret_cast<unsigned*>(&h01);
                u.y = *reinterpret_cast<unsigned*>(&h23);
                *reinterpret_cast<uint2*>(&drow[jbase + m * 16]) = u;
            }
        }
    } else {
        const float* Wv = (z == 2) ? Ws2 : We2;
        float* outh = (z == 2) ? out_start : out_end;
        float w[4];
#pragma unroll
        for (int n = 0; n < 4; ++n) w[n] = Wv[pcol[n]];
        const int rbase = r0 + wr * 128 + (lane >> 4) * 4;
#pragma unroll
        for (int m = 0; m < 8; ++m) {
#pragma unroll
            for (int q = 0; q < 4; ++q) {
                float s = 0.f;
#pragma unroll
                for (int n = 0; n < 4; ++n)
                    s += fmaxf(acc[m][n][q] + bq[n], 0.f) * w[n];
                s += __shfl_xor(s, 1); s += __shfl_xor(s, 2);
                s += __shfl_xor(s, 4); s += __shfl_xor(s, 8);
                if ((lane & 15) == 0)
                    atomicAdd(&outh[rbase + m * 16 + q], s);
            }
        }
    }
}

// ---------------------------------------------------------------------------
// bigram_kernel: partial[bz][i][j] = sum_{p in chunk pc} relu(l[j][p]+r[i][p])*Wo[p]
// bz = b*16 + pc (P split into 16 chunks of 32 -> 2048 blocks, 8/CU).
// f16 packed math: 2 cells per v_pk instruction. rs staged pre-duplicated
// {r,r}; ls pairs {l_j, l_j+1} read directly. Micro-tile 4i x 4j per thread.
// ---------------------------------------------------------------------------
__global__ __launch_bounds__(256) void bigram_kernel(
    const __half* __restrict__ left_h, const __half* __restrict__ right_h,
    const float* __restrict__ Wo, float* __restrict__ part)
{
    __shared__ __half ls[32][64];     // [p][j]  4 KB
    __shared__ __half2 rs2[32][64];   // [p][i] dup'd  8 KB
    __shared__ __half2 wos[32];

    const int bz = blockIdx.z, b = bz >> 4, pc = bz & 15;
    const int i0 = blockIdx.y * 64, j0 = blockIdx.x * 64;
    const int t = threadIdx.x, wid = t >> 6, lane = t & 63;
    const int tj = t & 15, ti = t >> 4;

    const __half* lbase = left_h  + (size_t)(b * kP + pc * 32) * kN;
    const __half* rbase = right_h + (size_t)(b * kP + pc * 32) * kN;

    // ls: direct global->LDS (linear dest, 1 KB per wave-call, 1 call/wave)
    {
        const int row = wid * 8 + (lane >> 3);
        __builtin_amdgcn_global_load_lds(
            (const __attribute__((address_space(1))) void*)
                (lbase + (size_t)row * kN + j0 + (lane & 7) * 8),
            (__attribute__((address_space(3))) void*)
                ((char*)&ls[0][0] + wid * 1024),
            16, 0, 0);
    }
    // rs2: reg-staged with in-register duplication {r,r}
    uint2 rload[2];
#pragma unroll
    for (int h = 0; h < 2; ++h) {
        const int idx = h * 256 + t, pp = idx >> 4, iq = idx & 15;
        rload[h] = *reinterpret_cast<const uint2*>(&rbase[(size_t)pp * kN + i0 + iq * 4]);
    }
    if (t < 32) wos[t] = __float2half2_rn(Wo[pc * 32 + t]);
#pragma unroll
    for (int h = 0; h < 2; ++h) {
        const int idx = h * 256 + t, pp = idx >> 4, iq = idx & 15;
        const unsigned lo = rload[h].x, hi = rload[h].y;
        uint4 d;
        d.x = (lo & 0xFFFFu) | (lo << 16);
        d.y = (lo >> 16)     | (lo & 0xFFFF0000u);
        d.z = (hi & 0xFFFFu) | (hi << 16);
        d.w = (hi >> 16)     | (hi & 0xFFFF0000u);
        *reinterpret_cast<uint4*>(&rs2[pp][iq * 4]) = d;
    }
    __syncthreads();

    const __half2 zero2 = __float2half2_rn(0.f);
    __half2 acc2[4][2];
#pragma unroll
    for (int ii = 0; ii < 4; ++ii)
#pragma unroll
        for (int jp = 0; jp < 2; ++jp) acc2[ii][jp] = zero2;

#pragma unroll 8
    for (int kk = 0; kk < 32; ++kk) {
        const __half2 wo2 = wos[kk];
        union { uint2 u; __half2 h[2]; } L;
        L.u = *reinterpret_cast<const uint2*>(&ls[kk][tj * 4]);
        union { uint4 u; __half2 h[4]; } R;
        R.u = *reinterpret_cast<const uint4*>(&rs2[kk][ti * 4]);
#pragma unroll
        for (int ii = 0; ii < 4; ++ii)
#pragma unroll
            for (int jp = 0; jp < 2; ++jp) {
                __half2 s = __hadd2(R.h[ii], L.h[jp]);
                s = pk_max2(s, zero2);
                acc2[ii][jp] = __hfma2(s, wo2, acc2[ii][jp]);
            }
    }

    float* po = part + (size_t)bz * 65536;
#pragma unroll
    for (int ii = 0; ii < 4; ++ii) {
        const float2 a = __half22float2(acc2[ii][0]);
        const float2 c = __half22float2(acc2[ii][1]);
        float4 o = {a.x, a.y, c.x, c.y};
        *reinterpret_cast<float4*>(&po[(i0 + ti * 4 + ii) * kN + j0 + tj * 4]) = o;
    }
}

// ---------------------------------------------------------------------------
// reduce_kernel: out[b][i][j] = bo + sum_{pc<16} part[b*16+pc][i][j]
// ---------------------------------------------------------------------------
__global__ __launch_bounds__(256) void reduce_kernel(
    const float* __restrict__ part, const float* __restrict__ bo,
    float* __restrict__ out)
{
    const int e4 = blockIdx.x * 256 + threadIdx.x;  // 0..131071
    const int e = e4 * 4, b = e >> 16, r = e & 65535;
    const float bias = bo[0];
    float4 acc = {bias, bias, bias, bias};
#pragma unroll
    for (int k = 0; k < 16; ++k) {
        const float4 v = *reinterpret_cast<const float4*>(
            &part[(size_t)(b * 16 + k) * 65536 + r]);
        acc.x += v.x; acc.y += v.y; acc.z += v.z; acc.w += v.w;
    }
    *reinterpret_cast<float4*>(&out[e]) = acc;
}

// ---------------------------------------------------------------------------
extern "C" void kernel_launch(void* const* d_in, const int* in_sizes, int n_in,
                              void* d_out, int out_size, void* d_ws, size_t ws_size,
                              hipStream_t stream) {
    const float* x   = (const float*)d_in[0];
    const float* Wl  = (const float*)d_in[1];
    const float* bl  = (const float*)d_in[2];
    const float* Wr  = (const float*)d_in[3];
    const float* Wo  = (const float*)d_in[4];
    const float* bo  = (const float*)d_in[5];
    const float* Ws1 = (const float*)d_in[6];
    const float* bs1 = (const float*)d_in[7];
    const float* Ws2 = (const float*)d_in[8];
    const float* bs2 = (const float*)d_in[9];
    const float* We1 = (const float*)d_in[10];
    const float* be1 = (const float*)d_in[11];
    const float* We2 = (const float*)d_in[12];
    const float* be2 = (const float*)d_in[13];

    float* out        = (float*)d_out;
    float* out_bigram = out;                          // [B,N,N,1]
    float* out_start  = out + (size_t)kB * kN * kN;   // [B,N,1]
    float* out_end    = out_start + (size_t)kB * kN;  // [B,N,1]

    // ws layout (36 MB total):
    //   0-2 MB   left_h  (f16, [b][p][j])
    //   2-4 MB   right_h (f16, [b][p][i])
    //   4-8 MB   xb (bf16)       } dead after proj_mfma
    //   8-12 MB  wb (bf16)       }
    //   4-36 MB  part (f32, 128x65536) -- aliases xb/wb, written by bigram
    __half* left_h  = (__half*)d_ws;
    __half* right_h = left_h + (size_t)1048576;
    unsigned short* xb = (unsigned short*)((char*)d_ws + (size_t)4 * 1024 * 1024);
    unsigned short* wb = xb + (size_t)2097152;
    float* part = (float*)((char*)d_ws + (size_t)4 * 1024 * 1024);

    cvt_kernel<<<2064, 256, 0, stream>>>(
        x, Wl, Wr, Ws1, We1, bs2, be2, xb, wb, out_start, out_end);

    proj_mfma<<<64, 512, 0, stream>>>(
        xb, wb, bl, bs1, be1, Ws2, We2, left_h, right_h, out_start, out_end);

    bigram_kernel<<<dim3(4, 4, 128), 256, 0, stream>>>(
        left_h, right_h, Wo, part);

    reduce_kernel<<<512, 256, 0, stream>>>(part, bo, out_bigram);
}

// Round 9
// 128.461 us; speedup vs baseline: 1.3002x; 1.1932x over previous
//
#include <hip/hip_runtime.h>
#include <hip/hip_fp16.h>

typedef __attribute__((ext_vector_type(8))) short short8;   // 8 bf16
typedef __attribute__((ext_vector_type(4))) float f32x4;    // MFMA acc

constexpr int kB = 8;
constexpr int kN = 256;
constexpr int kD = 1024;
constexpr int kP = 512;
constexpr int kM = kB * kN;  // 2048

// v_pk_max_f16 — ROCm headers lack __hmax2; emit the VOP3P op directly.
__device__ __forceinline__ __half2 pk_max2(__half2 a, __half2 b) {
    unsigned ua = *reinterpret_cast<unsigned*>(&a);
    unsigned ub = *reinterpret_cast<unsigned*>(&b);
    unsigned ur;
    asm("v_pk_max_f16 %0, %1, %2" : "=v"(ur) : "v"(ua), "v"(ub));
    return *reinterpret_cast<__half2*>(&ur);
}

// ---------------------------------------------------------------------------
// cvt_kernel: fp32 -> bf16 for x and the 4 projection weights (merged into
// one [2048][1024] matrix wb). Tail blocks (>=2048) init out_start/out_end
// with the head biases (proj_mfma atomicAdds partial head dots onto them).
// ---------------------------------------------------------------------------
__global__ __launch_bounds__(256) void cvt_kernel(
    const float* __restrict__ x,
    const float* __restrict__ Wl, const float* __restrict__ Wr,
    const float* __restrict__ Ws1, const float* __restrict__ We1,
    const float* __restrict__ bs2, const float* __restrict__ be2,
    unsigned short* __restrict__ xb, unsigned short* __restrict__ wb,
    float* __restrict__ out_start, float* __restrict__ out_end)
{
    const int bid = blockIdx.x;
    if (bid >= 2048) {  // head-bias init: 4096 elements
        const int idx = (bid - 2048) * 256 + threadIdx.x;
        if (idx < 2048) out_start[idx] = bs2[0];
        else            out_end[idx - 2048] = be2[0];
        return;
    }
    const int g = bid * 256 + threadIdx.x;  // 0..524287 groups of 8
    const float* src;
    unsigned short* dst;
    if (g < 262144) {
        src = x + (size_t)g * 8;
        dst = xb + (size_t)g * 8;
    } else {
        const int gg = g - 262144;
        const int w = gg >> 16;        // 0=Wl 1=Wr 2=Ws1 3=We1
        const int r = gg & 65535;
        const float* s = (w == 0) ? Wl : (w == 1) ? Wr : (w == 2) ? Ws1 : We1;
        src = s + (size_t)r * 8;
        dst = wb + ((size_t)w << 19) + (size_t)r * 8;
    }
    const float4 a = *reinterpret_cast<const float4*>(src);
    const float4 b = *reinterpret_cast<const float4*>(src + 4);
    const float v[8] = {a.x, a.y, a.z, a.w, b.x, b.y, b.z, b.w};
    short8 o;
#pragma unroll
    for (int i = 0; i < 8; ++i) {
        unsigned u = __float_as_uint(v[i]);
        u = u + 0x7FFF + ((u >> 16) & 1);  // RTNE
        o[i] = (short)(u >> 16);
    }
    *reinterpret_cast<short8*>(dst) = o;
}

// ---------------------------------------------------------------------------
// proj_mfma (R5 config — best measured ~18us): merged GEMM C[r][q].
// BM=BN=64, BK=64 -> grid 32x32 = 1024 blocks (4/CU). 4 waves (2x2), each
// wave a 32x32 output (2x2 fragments of 16x16x32, 2 k-subs per BK).
// LDS rows 128 B, XOR-swizzle byte^=(row&7)<<4 applied BOTH sides (rule #21).
// z = q0>>9: 0->left (bias bl, f16 transposed [b][p][j]); 1->right;
//            2,3->heads fused (relu, dot Ws2/We2, shfl-reduce, atomicAdd).
// ---------------------------------------------------------------------------
__global__ __launch_bounds__(256) void proj_mfma(
    const unsigned short* __restrict__ xb, const unsigned short* __restrict__ wb,
    const float* __restrict__ bl, const float* __restrict__ bs1,
    const float* __restrict__ be1,
    const float* __restrict__ Ws2, const float* __restrict__ We2,
    __half* __restrict__ left_h, __half* __restrict__ right_h,
    float* __restrict__ out_start, float* __restrict__ out_end)
{
    __shared__ unsigned short As[2][64 * 64];  // 8 KB x2
    __shared__ unsigned short Bs[2][64 * 64];  // 8 KB x2

    const int r0 = blockIdx.x * 64;
    const int q0 = blockIdx.y * 64;
    const int z  = q0 >> 9;
    const int t = threadIdx.x, wid = t >> 6, lane = t & 63;
    const int wr = wid >> 1, wc = wid & 1;

    f32x4 acc[2][2] = {};

    const int srow0 = wid * 16 + (lane >> 3);          // call 0 row
    const int scolh = ((lane & 7) ^ (lane >> 3)) << 3; // swizzled col (halves)
    const unsigned short* gA0 = xb + (size_t)(r0 + srow0) * kD + scolh;
    const unsigned short* gA1 = gA0 + (size_t)8 * kD;
    const unsigned short* gB0 = wb + (size_t)(q0 + srow0) * kD + scolh;
    const unsigned short* gB1 = gB0 + (size_t)8 * kD;

#define STAGE(buf, k0) do { \
    __builtin_amdgcn_global_load_lds( \
        (const __attribute__((address_space(1))) void*)(gA0 + (k0)), \
        (__attribute__((address_space(3))) void*)((char*)&As[buf][0] + wid * 2048), 16, 0, 0); \
    __builtin_amdgcn_global_load_lds( \
        (const __attribute__((address_space(1))) void*)(gA1 + (k0)), \
        (__attribute__((address_space(3))) void*)((char*)&As[buf][0] + wid * 2048 + 1024), 16, 0, 0); \
    __builtin_amdgcn_global_load_lds( \
        (const __attribute__((address_space(1))) void*)(gB0 + (k0)), \
        (__attribute__((address_space(3))) void*)((char*)&Bs[buf][0] + wid * 2048), 16, 0, 0); \
    __builtin_amdgcn_global_load_lds( \
        (const __attribute__((address_space(1))) void*)(gB1 + (k0)), \
        (__attribute__((address_space(3))) void*)((char*)&Bs[buf][0] + wid * 2048 + 1024), 16, 0, 0); \
} while (0)

    const int sw = (lane & 7) << 4;
    const int cb0 = (lane >> 4) * 16;
    const int rA = wr * 32 + (lane & 15);
    const int rB = wc * 32 + (lane & 15);

    STAGE(0, 0);
    __syncthreads();
    int cur = 0;
    for (int k0 = 0; k0 < kD; k0 += 64) {
        if (k0 + 64 < kD) STAGE(cur ^ 1, k0 + 64);
        short8 a[2][2], b[2][2];
#pragma unroll
        for (int m = 0; m < 2; ++m)
#pragma unroll
            for (int ks = 0; ks < 2; ++ks) {
                a[m][ks] = *reinterpret_cast<const short8*>(
                    (const char*)&As[cur][0] +
                    (rA + m * 16) * 128 + ((ks * 64 + cb0) ^ sw));
                b[m][ks] = *reinterpret_cast<const short8*>(
                    (const char*)&Bs[cur][0] +
                    (rB + m * 16) * 128 + ((ks * 64 + cb0) ^ sw));
            }
#pragma unroll
        for (int m = 0; m < 2; ++m)
#pragma unroll
            for (int n = 0; n < 2; ++n)
#pragma unroll
                for (int ks = 0; ks < 2; ++ks)
                    acc[m][n] = __builtin_amdgcn_mfma_f32_16x16x32_bf16(
                        a[m][ks], b[n][ks], acc[m][n], 0, 0, 0);
        __syncthreads();
        cur ^= 1;
    }
#undef STAGE

    // C/D layout: col = lane&15, row = (lane>>4)*4 + reg  [m89]
    int pcol[2]; float bq[2];
#pragma unroll
    for (int n = 0; n < 2; ++n) {
        pcol[n] = (q0 & 511) + wc * 32 + n * 16 + (lane & 15);
        bq[n] = (z == 0) ? bl[pcol[n]] : (z == 2) ? bs1[pcol[n]]
              : (z == 3) ? be1[pcol[n]] : 0.f;
    }
    if (z < 2) {
        __half* dst = (z == 0) ? left_h : right_h;
        const int bb = r0 >> 8;
        const int jbase = (r0 & 255) + wr * 32 + (lane >> 4) * 4;
#pragma unroll
        for (int n = 0; n < 2; ++n) {
            __half* drow = dst + (size_t)(bb * kP + pcol[n]) * kN;
#pragma unroll
            for (int m = 0; m < 2; ++m) {
                const f32x4 c = acc[m][n];
                __half2 h01 = __floats2half2_rn(c[0] + bq[n], c[1] + bq[n]);
                __half2 h23 = __floats2half2_rn(c[2] + bq[n], c[3] + bq[n]);
                uint2 u;
                u.x = *reinterpret_cast<unsigned*>(&h01);
                u.y = *reinterpret_cast<unsigned*>(&h23);
                *reinterpret_cast<uint2*>(&drow[jbase + m * 16]) = u;
            }
        }
    } else {
        const float* Wv = (z == 2) ? Ws2 : We2;
        float* outh = (z == 2) ? out_start : out_end;
        const float w0 = Wv[pcol[0]], w1 = Wv[pcol[1]];
        const int rbase = r0 + wr * 32 + (lane >> 4) * 4;
#pragma unroll
        for (int m = 0; m < 2; ++m) {
#pragma unroll
            for (int q = 0; q < 4; ++q) {
                float s = fmaxf(acc[m][0][q] + bq[0], 0.f) * w0 +
                          fmaxf(acc[m][1][q] + bq[1], 0.f) * w1;
                s += __shfl_xor(s, 1); s += __shfl_xor(s, 2);
                s += __shfl_xor(s, 4); s += __shfl_xor(s, 8);
                if ((lane & 15) == 0)
                    atomicAdd(&outh[rbase + m * 16 + q], s);
            }
        }
    }
}

// ---------------------------------------------------------------------------
// bigram_kernel (full-P, no partials): out[b][i][j] = bo +
//   sum_{p<512} relu(l[b][p][j] + r[b][p][i]) * Wo[p]
// Tile 32(i) x 32(j), grid 8x8x8 = 512 blocks (2/CU, 64KB LDS, one barrier).
// 256 threads = 16(tj) x 16(ti), micro 2j x 2i; f16 pk math, R duplicated
// per-use via v_perm. kk unrolled x2 with separate parity accumulators
// (f16 512-term accumulation error ~/sqrt(2)); merged ds_read2-friendly
// indexing. Each cell written exactly once -> direct store, no reduce.
// ---------------------------------------------------------------------------
__global__ __launch_bounds__(256) void bigram_kernel(
    const __half* __restrict__ left_h, const __half* __restrict__ right_h,
    const float* __restrict__ Wo, const float* __restrict__ bo,
    float* __restrict__ out)
{
    __shared__ __half ls[512][32];   // [p][j]  32 KB
    __shared__ __half rs[512][32];   // [p][i]  32 KB
    __shared__ __half2 wos2[512];    // dup'd Wo, 2 KB

    const int j0 = blockIdx.x * 32, i0 = blockIdx.y * 32, b = blockIdx.z;
    const int t = threadIdx.x, wid = t >> 6, lane = t & 63;
    const int tj = t & 15, ti = t >> 4;

    const __half* lbase = left_h  + (size_t)b * kP * kN + j0;
    const __half* rbase = right_h + (size_t)b * kP * kN + i0;

    // staging: 8 glds calls per wave per matrix (1 KB each, linear dest)
#pragma unroll
    for (int c = 0; c < 8; ++c) {
        const int seg = c * 4 + wid;                 // 0..31 -> rows seg*16..+15
        const int row = seg * 16 + (lane >> 2);
        const int jo  = (lane & 3) * 8;              // halves
        __builtin_amdgcn_global_load_lds(
            (const __attribute__((address_space(1))) void*)
                (lbase + (size_t)row * kN + jo),
            (__attribute__((address_space(3))) void*)
                ((char*)&ls[0][0] + seg * 1024),
            16, 0, 0);
        __builtin_amdgcn_global_load_lds(
            (const __attribute__((address_space(1))) void*)
                (rbase + (size_t)row * kN + jo),
            (__attribute__((address_space(3))) void*)
                ((char*)&rs[0][0] + seg * 1024),
            16, 0, 0);
    }
    wos2[t]       = __float2half2_rn(Wo[t]);
    wos2[t + 256] = __float2half2_rn(Wo[t + 256]);
    __syncthreads();

    const unsigned* lsu = (const unsigned*)&ls[0][0];  // row stride 16 dwords
    const unsigned* rsu = (const unsigned*)&rs[0][0];

    __half2 accA[2] = {__half2{0,0}, __half2{0,0}};
    __half2 accB[2] = {__half2{0,0}, __half2{0,0}};

#pragma unroll 8
    for (int kk = 0; kk < 512; kk += 2) {
        // adjacent-kk LDS reads (64 B apart) -> ds_read2_b32 mergeable
        const unsigned L0 = lsu[kk * 16 + tj];
        const unsigned L1 = lsu[(kk + 1) * 16 + tj];
        const unsigned R0 = rsu[kk * 16 + ti];
        const unsigned R1 = rsu[(kk + 1) * 16 + ti];
        const __half2 w0 = wos2[kk], w1 = wos2[kk + 1];

        const unsigned r00 = __builtin_amdgcn_perm(R0, R0, 0x01000100);
        const unsigned r01 = __builtin_amdgcn_perm(R0, R0, 0x03020302);
        const unsigned r10 = __builtin_amdgcn_perm(R1, R1, 0x01000100);
        const unsigned r11 = __builtin_amdgcn_perm(R1, R1, 0x03020302);

        const __half2 l0 = *reinterpret_cast<const __half2*>(&L0);
        const __half2 l1 = *reinterpret_cast<const __half2*>(&L1);
        const __half2 zero2 = __half2{0, 0};

        accA[0] = __hfma2(pk_max2(__hadd2(*reinterpret_cast<const __half2*>(&r00), l0), zero2), w0, accA[0]);
        accA[1] = __hfma2(pk_max2(__hadd2(*reinterpret_cast<const __half2*>(&r01), l0), zero2), w0, accA[1]);
        accB[0] = __hfma2(pk_max2(__hadd2(*reinterpret_cast<const __half2*>(&r10), l1), zero2), w1, accB[0]);
        accB[1] = __hfma2(pk_max2(__hadd2(*reinterpret_cast<const __half2*>(&r11), l1), zero2), w1, accB[1]);
    }

    const float bias = bo[0];
#pragma unroll
    for (int ii = 0; ii < 2; ++ii) {
        const float2 fa = __half22float2(accA[ii]);
        const float2 fb = __half22float2(accB[ii]);
        float2 o = {fa.x + fb.x + bias, fa.y + fb.y + bias};
        const int i = i0 + ti * 2 + ii;
        *reinterpret_cast<float2*>(
            &out[((size_t)b * kN + i) * kN + j0 + tj * 2]) = o;
    }
}

// ---------------------------------------------------------------------------
extern "C" void kernel_launch(void* const* d_in, const int* in_sizes, int n_in,
                              void* d_out, int out_size, void* d_ws, size_t ws_size,
                              hipStream_t stream) {
    const float* x   = (const float*)d_in[0];
    const float* Wl  = (const float*)d_in[1];
    const float* bl  = (const float*)d_in[2];
    const float* Wr  = (const float*)d_in[3];
    const float* Wo  = (const float*)d_in[4];
    const float* bo  = (const float*)d_in[5];
    const float* Ws1 = (const float*)d_in[6];
    const float* bs1 = (const float*)d_in[7];
    const float* Ws2 = (const float*)d_in[8];
    const float* bs2 = (const float*)d_in[9];
    const float* We1 = (const float*)d_in[10];
    const float* be1 = (const float*)d_in[11];
    const float* We2 = (const float*)d_in[12];
    const float* be2 = (const float*)d_in[13];

    float* out        = (float*)d_out;
    float* out_bigram = out;                          // [B,N,N,1]
    float* out_start  = out + (size_t)kB * kN * kN;   // [B,N,1]
    float* out_end    = out_start + (size_t)kB * kN;  // [B,N,1]

    // ws layout (12 MB used):
    //   0-2 MB   left_h  (f16, [b][p][j])
    //   2-4 MB   right_h (f16, [b][p][i])
    //   4-8 MB   xb (bf16)
    //   8-12 MB  wb (bf16)
    __half* left_h  = (__half*)d_ws;
    __half* right_h = left_h + (size_t)1048576;
    unsigned short* xb = (unsigned short*)((char*)d_ws + (size_t)4 * 1024 * 1024);
    unsigned short* wb = xb + (size_t)2097152;

    cvt_kernel<<<2064, 256, 0, stream>>>(
        x, Wl, Wr, Ws1, We1, bs2, be2, xb, wb, out_start, out_end);

    proj_mfma<<<dim3(32, 32), 256, 0, stream>>>(
        xb, wb, bl, bs1, be1, Ws2, We2, left_h, right_h, out_start, out_end);

    bigram_kernel<<<dim3(8, 8, 8), 256, 0, stream>>>(
        left_h, right_h, Wo, bo, out_bigram);
}